// Round 1
// baseline (4830.072 us; speedup 1.0000x reference)
//
#include <hip/hip_runtime.h>
#include <hip/hip_bf16.h>

// Problem constants
#define Ecst 512
#define Hcst 512
#define Vcst 32000
#define Bcst 64
#define Tcst 32
#define Lcst 49

typedef __attribute__((ext_vector_type(8))) short short8;
typedef __attribute__((ext_vector_type(4))) float f32x4;

__device__ __forceinline__ float bf2f(unsigned short u) {
    union { unsigned int i; float f; } x; x.i = ((unsigned int)u) << 16; return x.f;
}
__device__ __forceinline__ float sigm(float x) { return 1.f / (1.f + __expf(-x)); }

// ---------------------------------------------------------------------------
// Prep: convert weights to bf16, gather caption embeddings (bf16), zero states
// ---------------------------------------------------------------------------
__global__ void k_prep(const float* __restrict__ wih1, const float* __restrict__ whh1,
                       const float* __restrict__ wih2, const float* __restrict__ whh2,
                       const float* __restrict__ wcat, const float* __restrict__ wout,
                       const float* __restrict__ embt, const int* __restrict__ caps,
                       __hip_bfloat16* __restrict__ WL, __hip_bfloat16* __restrict__ WC,
                       __hip_bfloat16* __restrict__ WO, __hip_bfloat16* __restrict__ EMB,
                       unsigned int* __restrict__ zero_region)
{
    const long long NW = 1048576;           // 2048*512
    const long long total = 22284288;       // 4*NW + 524288 + 16384000 + 1048576 + 133120
    for (long long i = (long long)blockIdx.x * blockDim.x + threadIdx.x; i < total;
         i += (long long)gridDim.x * blockDim.x) {
        long long idx = i;
        if (idx < 4 * NW) {
            const float* src = (idx < NW) ? wih1 : (idx < 2*NW) ? whh1 : (idx < 3*NW) ? wih2 : whh2;
            WL[idx] = __float2bfloat16(src[idx & (NW - 1)]);
        } else if ((idx -= 4 * NW) < 524288) {
            WC[idx] = __float2bfloat16(wcat[idx]);
        } else if ((idx -= 524288) < 16384000) {
            WO[idx] = __float2bfloat16(wout[idx]);
        } else if ((idx -= 16384000) < 1048576) {
            int k = (int)(idx & 511);
            int p = (int)(idx >> 9);        // p = t*64 + b
            int tt = p >> 6, b = p & 63;
            int cap = caps[b * Tcst + tt];
            EMB[idx] = __float2bfloat16(embt[(long long)cap * Ecst + k]);
        } else {
            idx -= 1048576;                 // < 133120 words: c1,c2,h1(x2),h2(x2),sums
            zero_region[idx] = 0u;
        }
    }
}

// ---------------------------------------------------------------------------
// Fused LSTM cell: gates[64,2048] = A0@Wa^T + A1@Wb^T + biases, then update.
// Grid: 32 blocks x 64 threads (1 wave). Block bu owns units [bu*16, bu*16+16).
// Wave: 4 m-tiles (batch 0..63) x 4 n-tiles (gate types i,f,g,o of same units)
// ---------------------------------------------------------------------------
__global__ void k_lstm(const __hip_bfloat16* __restrict__ A0, const __hip_bfloat16* __restrict__ A1,
                       const __hip_bfloat16* __restrict__ Wa, const __hip_bfloat16* __restrict__ Wb,
                       const float* __restrict__ bih, const float* __restrict__ bhh,
                       float* __restrict__ c, __hip_bfloat16* __restrict__ hout)
{
    int lane = threadIdx.x;
    int lr = lane & 15, lq = lane >> 4;
    int u = blockIdx.x * 16 + lr;           // unit owned by this lane (C/D col)

    f32x4 acc[4][4] = {};                   // [m-tile][gate]
    const short8* Av0 = (const short8*)A0;  // rows of 64 short8 (512 bf16)
    const short8* Av1 = (const short8*)A1;
    const short8* Wv0 = (const short8*)Wa;
    const short8* Wv1 = (const short8*)Wb;

    for (int ks = 0; ks < 16; ++ks) {       // K-half 0: A0 @ Wa^T
        int kv = ks * 4 + lq;
        short8 a[4], wv[4];
#pragma unroll
        for (int mt = 0; mt < 4; ++mt) a[mt] = Av0[(mt * 16 + lr) * 64 + kv];
#pragma unroll
        for (int g = 0; g < 4; ++g) wv[g] = Wv0[(size_t)(g * 512 + u) * 64 + kv];
#pragma unroll
        for (int mt = 0; mt < 4; ++mt)
#pragma unroll
            for (int g = 0; g < 4; ++g)
                acc[mt][g] = __builtin_amdgcn_mfma_f32_16x16x32_bf16(a[mt], wv[g], acc[mt][g], 0, 0, 0);
    }
    for (int ks = 0; ks < 16; ++ks) {       // K-half 1: A1 @ Wb^T
        int kv = ks * 4 + lq;
        short8 a[4], wv[4];
#pragma unroll
        for (int mt = 0; mt < 4; ++mt) a[mt] = Av1[(mt * 16 + lr) * 64 + kv];
#pragma unroll
        for (int g = 0; g < 4; ++g) wv[g] = Wv1[(size_t)(g * 512 + u) * 64 + kv];
#pragma unroll
        for (int mt = 0; mt < 4; ++mt)
#pragma unroll
            for (int g = 0; g < 4; ++g)
                acc[mt][g] = __builtin_amdgcn_mfma_f32_16x16x32_bf16(a[mt], wv[g], acc[mt][g], 0, 0, 0);
    }

    float bi = bih[u] + bhh[u];
    float bf = bih[512 + u] + bhh[512 + u];
    float bg = bih[1024 + u] + bhh[1024 + u];
    float bo = bih[1536 + u] + bhh[1536 + u];
#pragma unroll
    for (int mt = 0; mt < 4; ++mt)
#pragma unroll
        for (int r = 0; r < 4; ++r) {
            int m = mt * 16 + lq * 4 + r;   // C/D row = batch
            float iv = acc[mt][0][r] + bi;
            float fv = acc[mt][1][r] + bf;
            float gv = acc[mt][2][r] + bg;
            float ov = acc[mt][3][r] + bo;
            int off = m * Hcst + u;
            float co = c[off];
            float cn = sigm(fv) * co + sigm(iv) * tanhf(gv);
            c[off] = cn;
            hout[off] = __float2bfloat16(sigm(ov) * tanhf(cn));
        }
}

// ---------------------------------------------------------------------------
// Attention + concat projection. Grid: 64 blocks (one per batch) x 256.
// ---------------------------------------------------------------------------
__global__ void k_attn(const float* __restrict__ feats, const __hip_bfloat16* __restrict__ h2,
                       const __hip_bfloat16* __restrict__ wcat, const float* __restrict__ bcat,
                       __hip_bfloat16* __restrict__ ccat)
{
    __shared__ float h2s[512];
    __shared__ float cats[1024];
    __shared__ float sm[64];
    int b = blockIdx.x, tid = threadIdx.x;
    for (int k = tid; k < 512; k += 256) h2s[k] = __bfloat162float(h2[b * Hcst + k]);
    __syncthreads();
    int w = tid >> 6, lane = tid & 63;
    const float* fb = feats + (size_t)b * (Lcst * Hcst);
    // scores[l] = features[b,l,:] . h2
    for (int l = w; l < Lcst; l += 4) {
        const float4* f4 = (const float4*)(fb + l * Hcst + lane * 8);
        float4 x0 = f4[0], x1 = f4[1];
        int k0 = lane * 8;
        float s = x0.x * h2s[k0] + x0.y * h2s[k0 + 1] + x0.z * h2s[k0 + 2] + x0.w * h2s[k0 + 3] +
                  x1.x * h2s[k0 + 4] + x1.y * h2s[k0 + 5] + x1.z * h2s[k0 + 6] + x1.w * h2s[k0 + 7];
#pragma unroll
        for (int m = 32; m; m >>= 1) s += __shfl_xor(s, m);
        if (lane == 0) sm[l] = s;
    }
    __syncthreads();
    if (w == 0) {   // softmax over 49 regions, single wave
        float s = (lane < Lcst) ? sm[lane] : -1e30f;
        float mx = s;
#pragma unroll
        for (int m = 32; m; m >>= 1) mx = fmaxf(mx, __shfl_xor(mx, m));
        float e = (lane < Lcst) ? __expf(s - mx) : 0.f;
        float su = e;
#pragma unroll
        for (int m = 32; m; m >>= 1) su += __shfl_xor(su, m);
        if (lane < Lcst) sm[lane] = e / su;
    }
    __syncthreads();
    // context[k] = sum_l attn[l]*features[b,l,k]; cat = [context, h2]
    for (int k = tid; k < 512; k += 256) {
        float cx = 0.f;
#pragma unroll 7
        for (int l = 0; l < Lcst; ++l) cx += sm[l] * fb[l * Hcst + k];
        cats[k] = cx;
        cats[512 + k] = h2s[k];
    }
    __syncthreads();
    // concat[j] = tanh(cat . W_cat[j,:] + b_cat[j])   (K=1024, bf16 weights)
    for (int j = tid; j < 512; j += 256) {
        const short8* wr = (const short8*)(wcat + (size_t)j * 1024);
        float acc = bcat[j];
        for (int kk = 0; kk < 128; ++kk) {
            short8 wv = wr[kk];
            int kb = kk * 8;
            acc += bf2f((unsigned short)wv[0]) * cats[kb] +
                   bf2f((unsigned short)wv[1]) * cats[kb + 1] +
                   bf2f((unsigned short)wv[2]) * cats[kb + 2] +
                   bf2f((unsigned short)wv[3]) * cats[kb + 3] +
                   bf2f((unsigned short)wv[4]) * cats[kb + 4] +
                   bf2f((unsigned short)wv[5]) * cats[kb + 5] +
                   bf2f((unsigned short)wv[6]) * cats[kb + 6] +
                   bf2f((unsigned short)wv[7]) * cats[kb + 7];
        }
        ccat[b * Hcst + j] = __float2bfloat16(tanhf(acc));
    }
}

// ---------------------------------------------------------------------------
// Output GEMM: logits[64, 32000] = concat @ W_out^T + b_out, raw logits to
// d_out, per-(t,b) sum(exp(logit)) atomically accumulated.
// Grid: 250 blocks x 256 (4 waves, each wave 2 n-tiles of 16).
// ---------------------------------------------------------------------------
__global__ void k_logits(const __hip_bfloat16* __restrict__ ccat, const __hip_bfloat16* __restrict__ wo,
                         const float* __restrict__ bout, float* __restrict__ out,
                         float* __restrict__ sums, int t)
{
    __shared__ float sml[64];
    int tid = threadIdx.x;
    int lane = tid & 63, lr = lane & 15, lq = lane >> 4, w = tid >> 6;
    if (tid < 64) sml[tid] = 0.f;
    __syncthreads();
    int nbase = blockIdx.x * 128 + w * 32;
    f32x4 acc[4][2] = {};
    const short8* Av = (const short8*)ccat;
    const short8* Bv = (const short8*)wo;
    for (int ks = 0; ks < 16; ++ks) {
        int kv = ks * 4 + lq;
        short8 a0 = Av[lr * 64 + kv];
        short8 a1 = Av[(16 + lr) * 64 + kv];
        short8 a2 = Av[(32 + lr) * 64 + kv];
        short8 a3 = Av[(48 + lr) * 64 + kv];
        short8 b0 = Bv[(size_t)(nbase + lr) * 64 + kv];
        short8 b1 = Bv[(size_t)(nbase + 16 + lr) * 64 + kv];
        acc[0][0] = __builtin_amdgcn_mfma_f32_16x16x32_bf16(a0, b0, acc[0][0], 0, 0, 0);
        acc[1][0] = __builtin_amdgcn_mfma_f32_16x16x32_bf16(a1, b0, acc[1][0], 0, 0, 0);
        acc[2][0] = __builtin_amdgcn_mfma_f32_16x16x32_bf16(a2, b0, acc[2][0], 0, 0, 0);
        acc[3][0] = __builtin_amdgcn_mfma_f32_16x16x32_bf16(a3, b0, acc[3][0], 0, 0, 0);
        acc[0][1] = __builtin_amdgcn_mfma_f32_16x16x32_bf16(a0, b1, acc[0][1], 0, 0, 0);
        acc[1][1] = __builtin_amdgcn_mfma_f32_16x16x32_bf16(a1, b1, acc[1][1], 0, 0, 0);
        acc[2][1] = __builtin_amdgcn_mfma_f32_16x16x32_bf16(a2, b1, acc[2][1], 0, 0, 0);
        acc[3][1] = __builtin_amdgcn_mfma_f32_16x16x32_bf16(a3, b1, acc[3][1], 0, 0, 0);
    }
    float bo0 = bout[nbase + lr], bo1 = bout[nbase + 16 + lr];
#pragma unroll
    for (int mt = 0; mt < 4; ++mt)
#pragma unroll
        for (int r = 0; r < 4; ++r) {
            int m = mt * 16 + lq * 4 + r;
            float l0 = acc[mt][0][r] + bo0;
            float l1 = acc[mt][1][r] + bo1;
            size_t o = ((size_t)m * Tcst + t) * Vcst;
            out[o + nbase + lr] = l0;
            out[o + nbase + 16 + lr] = l1;
            // logits are tiny (|x| << 10): exp without max-subtraction is safe
            float e = __expf(l0) + __expf(l1);
            e += __shfl_xor(e, 1); e += __shfl_xor(e, 2);
            e += __shfl_xor(e, 4); e += __shfl_xor(e, 8);
            if (lr == 0) atomicAdd(&sml[m], e);
        }
    __syncthreads();
    if (tid < 64) atomicAdd(&sums[t * 64 + tid], sml[tid]);
}

__global__ void k_lse(float* __restrict__ sums)
{
    int i = blockIdx.x * blockDim.x + threadIdx.x;
    if (i < Tcst * Bcst) sums[i] = logf(sums[i]);
}

__global__ void k_norm(float* __restrict__ out, const float* __restrict__ lse)
{
    const unsigned total4 = 16384000u;   // 64*32*32000 / 4
    for (unsigned i = blockIdx.x * blockDim.x + threadIdx.x; i < total4;
         i += gridDim.x * blockDim.x) {
        float4 v = ((float4*)out)[i];
        unsigned bt = (i * 4u) / 32000u;                // b*32 + t (rows are /4 aligned)
        float ls = lse[(bt & 31) * 64 + (bt >> 5)];     // lse[t*64 + b]
        v.x -= ls; v.y -= ls; v.z -= ls; v.w -= ls;
        ((float4*)out)[i] = v;
    }
}

// ---------------------------------------------------------------------------
extern "C" void kernel_launch(void* const* d_in, const int* in_sizes, int n_in,
                              void* d_out, int out_size, void* d_ws, size_t ws_size,
                              hipStream_t stream)
{
    (void)in_sizes; (void)n_in; (void)out_size; (void)ws_size;
    const float* features = (const float*)d_in[0];
    const int*   captions = (const int*)d_in[1];
    const float* embed_t  = (const float*)d_in[2];
    const float* wih1 = (const float*)d_in[3];
    const float* whh1 = (const float*)d_in[4];
    const float* bih1 = (const float*)d_in[5];
    const float* bhh1 = (const float*)d_in[6];
    const float* wih2 = (const float*)d_in[7];
    const float* whh2 = (const float*)d_in[8];
    const float* bih2 = (const float*)d_in[9];
    const float* bhh2 = (const float*)d_in[10];
    const float* wcat = (const float*)d_in[11];
    const float* bcat = (const float*)d_in[12];
    const float* wout = (const float*)d_in[13];
    const float* bout = (const float*)d_in[14];
    float* out = (float*)d_out;

    // workspace layout (bytes)
    char* ws = (char*)d_ws;
    __hip_bfloat16* WL   = (__hip_bfloat16*)(ws);              // 4 LSTM weights, 8,388,608 B
    __hip_bfloat16* WC   = (__hip_bfloat16*)(ws + 8388608);    // W_cat bf16, 1,048,576 B
    __hip_bfloat16* WO   = (__hip_bfloat16*)(ws + 9437184);    // W_out bf16, 32,768,000 B
    __hip_bfloat16* EMB  = (__hip_bfloat16*)(ws + 42205184);   // [T][B][512] bf16, 2,097,152 B
    float*          C1   = (float*)(ws + 44302336);            // 131,072 B
    float*          C2   = (float*)(ws + 44433408);            // 131,072 B
    __hip_bfloat16* H1   = (__hip_bfloat16*)(ws + 44564480);   // 2 slots, 131,072 B
    __hip_bfloat16* H2   = (__hip_bfloat16*)(ws + 44695552);   // 2 slots, 131,072 B
    float*          SUMS = (float*)(ws + 44826624);            // [T][B], 8,192 B
    __hip_bfloat16* CCAT = (__hip_bfloat16*)(ws + 44834816);   // 65,536 B
    unsigned int*   ZERO = (unsigned int*)C1;                  // 133,120 words: C1..SUMS

    k_prep<<<4096, 256, 0, stream>>>(wih1, whh1, wih2, whh2, wcat, wout, embed_t, captions,
                                     WL, WC, WO, EMB, ZERO);

    const int NW = 2048 * 512;
    const int HS = Bcst * Hcst;   // 32768, one h-slot
    for (int t = 0; t < Tcst; ++t) {
        __hip_bfloat16* h1o = H1 + (t & 1) * HS;
        __hip_bfloat16* h1n = H1 + ((t + 1) & 1) * HS;
        __hip_bfloat16* h2o = H2 + (t & 1) * HS;
        __hip_bfloat16* h2n = H2 + ((t + 1) & 1) * HS;
        k_lstm<<<32, 64, 0, stream>>>(EMB + t * HS, h1o, WL, WL + NW, bih1, bhh1, C1, h1n);
        k_lstm<<<32, 64, 0, stream>>>(h1n, h2o, WL + 2 * NW, WL + 3 * NW, bih2, bhh2, C2, h2n);
        k_attn<<<64, 256, 0, stream>>>(features, h2n, WC, bcat, CCAT);
        k_logits<<<250, 256, 0, stream>>>(CCAT, WO, bout, out, SUMS, t);
    }
    k_lse<<<8, 256, 0, stream>>>(SUMS);
    k_norm<<<4096, 256, 0, stream>>>(out, SUMS);
}